// Round 2
// 472.394 us; speedup vs baseline: 1.0249x; 1.0249x over previous
//
#include <hip/hip_runtime.h>
#include <hip/hip_bf16.h>

// Shapes (fixed by reference): B=32, N=12, S=512, D=256, A=96
#define B_ 32
#define N_ 12
#define S_ 512
#define D_ 256
#define A_ 96

typedef __attribute__((ext_vector_type(8))) short short8;   // 8 bf16 (4 VGPRs)
typedef __attribute__((ext_vector_type(4))) float float4v;  // MFMA acc

// fp32 -> bf16 round-to-nearest-even (data has no NaN/Inf)
static __device__ __forceinline__ ushort f2bf(float f) {
  union { float f; unsigned u; } a;
  a.f = f;
  return (ushort)((a.u + 0x7FFFu + ((a.u >> 16) & 1u)) >> 16);
}

// ---------------------------------------------------------------------------
// Kernel 1: qk = emb @ Wqk + bqk  [N,S,D] fp32 (for kernel 2), and
//           q = softmax(qk, d) written bf16 [n][s][d].
// ---------------------------------------------------------------------------
__global__ __launch_bounds__(256) void k_qk_softmax_q(
    const float* __restrict__ emb, const float* __restrict__ Wqk,
    const float* __restrict__ bqk, float* __restrict__ qk,
    ushort* __restrict__ qb) {
  int ns = blockIdx.x;
  int d = threadIdx.x;
  __shared__ float se[A_];
  __shared__ float red[8];
  if (d < A_) se[d] = emb[ns * A_ + d];
  __syncthreads();
  float acc = bqk[d];
#pragma unroll
  for (int a = 0; a < A_; ++a) acc = fmaf(se[a], Wqk[a * D_ + d], acc);
  qk[ns * D_ + d] = acc;
  float m = acc;
  for (int off = 32; off; off >>= 1) m = fmaxf(m, __shfl_xor(m, off));
  if ((d & 63) == 0) red[d >> 6] = m;
  __syncthreads();
  m = fmaxf(fmaxf(red[0], red[1]), fmaxf(red[2], red[3]));
  float e = __expf(acc - m);
  float sum = e;
  for (int off = 32; off; off >>= 1) sum += __shfl_xor(sum, off);
  if ((d & 63) == 0) red[4 + (d >> 6)] = sum;
  __syncthreads();
  sum = red[4] + red[5] + red[6] + red[7];
  qb[ns * D_ + d] = f2bf(e / sum);
}

// ---------------------------------------------------------------------------
// Kernel 2: kT[n][d][s] = softmax over s of qk[n][s][d], bf16 output.
// ---------------------------------------------------------------------------
__global__ __launch_bounds__(256) void k_softmax_kT(
    const float* __restrict__ qk, ushort* __restrict__ kTb) {
  int d = blockIdx.x;
  int n = blockIdx.y;
  int s = threadIdx.x;
  __shared__ float red[8];
  float v0 = qk[(n * S_ + s) * D_ + d];
  float v1 = qk[(n * S_ + s + 256) * D_ + d];
  float m = fmaxf(v0, v1);
  for (int off = 32; off; off >>= 1) m = fmaxf(m, __shfl_xor(m, off));
  if ((s & 63) == 0) red[s >> 6] = m;
  __syncthreads();
  m = fmaxf(fmaxf(red[0], red[1]), fmaxf(red[2], red[3]));
  float e0 = __expf(v0 - m), e1 = __expf(v1 - m);
  float sum = e0 + e1;
  for (int off = 32; off; off >>= 1) sum += __shfl_xor(sum, off);
  if ((s & 63) == 0) red[4 + (s >> 6)] = sum;
  __syncthreads();
  sum = red[4] + red[5] + red[6] + red[7];
  float inv = 1.0f / sum;
  kTb[(n * D_ + d) * S_ + s] = f2bf(e0 * inv);
  kTb[(n * D_ + d) * S_ + s + 256] = f2bf(e1 * inv);
}

// ---------------------------------------------------------------------------
// Kernel 3: WvT[c][e] = bf16(Wv[e][c])  (tiny: 256x256)
// ---------------------------------------------------------------------------
__global__ __launch_bounds__(256) void k_wvt(const float* __restrict__ Wv,
                                             ushort* __restrict__ WvT) {
  int c = blockIdx.x, e = threadIdx.x;
  WvT[c * D_ + e] = f2bf(Wv[e * D_ + c]);
}

// ---------------------------------------------------------------------------
// Kernel 4: kv0[bz][d][e] = sum_s kT[n][d][s] * value[bz][s][e]  (bf16 MFMA)
// C[m=e][n=d]: A = value^T rows e (transpose+cvt staging), B = kT rows d.
// Block: e-tile 64 (blockIdx.x 0..3) x FULL d=256 -> value read exactly ONCE.
// 4 waves split n=d (64 each); per-wave 64x64 = acc[4][4]; BK=64.
// Packed [n][m] epilogue lands kv0[d][e] with e 4-contiguous.
// ---------------------------------------------------------------------------
__global__ __launch_bounds__(256) void k_kv0(
    const ushort* __restrict__ kTb, const float* __restrict__ value,
    ushort* __restrict__ kv0) {
  const int eb = blockIdx.x * 64;  // e-tile base (0..3)
  const int bz = blockIdx.y;       // b*N+n
  const int n = bz % N_;
  const int tid = threadIdx.x;
  const int l = tid & 63, w = tid >> 6;
  const int lane16 = l & 15, quad = l >> 4;

  __shared__ ushort ldsV[64 * 72];   // valueT tile [e_local][s_local]
  __shared__ ushort ldsK[256 * 72];  // kT tile     [d][s_local]

  float4v acc[4][4];
#pragma unroll
  for (int i = 0; i < 4; ++i)
#pragma unroll
    for (int j = 0; j < 4; ++j) acc[i][j] = (float4v)0.0f;

  const ushort* kTbase = kTb + (size_t)n * D_ * S_;
  const float* vbase = value + (size_t)bz * S_ * D_ + eb;

  for (int sc = 0; sc < S_; sc += 64) {
    __syncthreads();
    // stage K: 256 rows x 64 cols bf16, natural copy, 16B chunks
#pragma unroll
    for (int it = 0; it < 8; ++it) {
      int id = it * 256 + tid;
      int rd = id >> 3, cc = (id & 7) * 8;
      *(uint4*)(&ldsK[rd * 72 + cc]) =
          *(const uint4*)(kTbase + rd * S_ + sc + cc);
    }
    // stage V transposed: read value[s][e] coalesced, write ldsV[e][s]
#pragma unroll
    for (int it = 0; it < 8; ++it) {
      int id = it * 256 + tid;
      int e = id & 63, sp = id >> 6;  // sp: s-pair 0..31
      float f0 = vbase[(sc + 2 * sp) * D_ + e];
      float f1 = vbase[(sc + 2 * sp + 1) * D_ + e];
      ushort2 p;
      p.x = f2bf(f0);
      p.y = f2bf(f1);
      *(ushort2*)(&ldsV[e * 72 + 2 * sp]) = p;
    }
    __syncthreads();
#pragma unroll
    for (int kc = 0; kc < 64; kc += 32) {
      int ko = kc + quad * 8;
      short8 a[4], b[4];
#pragma unroll
      for (int i = 0; i < 4; ++i)  // A rows m = e_local
        a[i] = *(const short8*)(&ldsV[(i * 16 + lane16) * 72 + ko]);
#pragma unroll
      for (int j = 0; j < 4; ++j)  // B rows n = d
        b[j] = *(const short8*)(&ldsK[(w * 64 + j * 16 + lane16) * 72 + ko]);
#pragma unroll
      for (int i = 0; i < 4; ++i)
#pragma unroll
        for (int j = 0; j < 4; ++j)
          acc[i][j] = __builtin_amdgcn_mfma_f32_16x16x32_bf16(a[i], b[j],
                                                              acc[i][j], 0, 0, 0);
    }
  }
  // epilogue: n = d = w*64+j*16+lane16; m = e = eb+i*16+quad*4+r -> kv0[d][e]
  ushort* obase = kv0 + (size_t)bz * D_ * D_;
#pragma unroll
  for (int i = 0; i < 4; ++i) {
#pragma unroll
    for (int j = 0; j < 4; ++j) {
      int d = w * 64 + j * 16 + lane16;
      int e0 = eb + i * 16 + quad * 4;
      ushort4 p;
      p.x = f2bf(acc[i][j][0]);
      p.y = f2bf(acc[i][j][1]);
      p.z = f2bf(acc[i][j][2]);
      p.w = f2bf(acc[i][j][3]);
      *(ushort4*)(obase + d * D_ + e0) = p;
    }
  }
}

// ---------------------------------------------------------------------------
// Kernel 5: IN-PLACE kvW transform (keeps workspace at proven 63 MB).
//   Reads  kv0[bz][128h : 128h+128][e=0..255]           (its own region ONLY)
//   Writes same region as kvWT'[c=0..255][d_local=0..127] = kv0@Wv + bv fold.
// Safe: row d of kv0@Wv depends only on row d of kv0; one block owns the
// whole (bz, d-half) region; all its global reads complete (staging+barrier)
// before the epilogue overwrites. Stream order isolates k4 -> k5 -> k6.
// Associativity win retained: out = q@(kv0@Wv) saves 12.9 GF vs (q@kv0)@Wv;
// bv folds exactly since softmax rows of q sum to 1.
// C[m=d_local][n=c]: A = kv0 rows d (natural), B = WvT rows c (natural).
// 4 waves: wave w owns c in [64w,64w+64); m covered by 2 subtiles of 64.
// ---------------------------------------------------------------------------
__global__ __launch_bounds__(256) void k_kvw_inplace(
    ushort* kv0, const ushort* __restrict__ WvT,
    const float* __restrict__ bv) {
  const int h = blockIdx.x;   // d-half (0..1)
  const int bz = blockIdx.y;  // b*N+n
  const int tid = threadIdx.x;
  const int l = tid & 63, w = tid >> 6;
  const int lane16 = l & 15, quad = l >> 4;

  __shared__ ushort ldsA[128 * 72];  // kv0 rows d_local x e-chunk
  __shared__ ushort ldsB[256 * 72];  // WvT rows c x e-chunk

  float4v acc[2][4][4];
#pragma unroll
  for (int m = 0; m < 2; ++m)
#pragma unroll
    for (int i = 0; i < 4; ++i)
#pragma unroll
      for (int j = 0; j < 4; ++j) acc[m][i][j] = (float4v)0.0f;

  ushort* base = kv0 + (size_t)bz * (D_ * D_) + h * (128 * D_);

  for (int ec = 0; ec < D_; ec += 64) {
    __syncthreads();
#pragma unroll
    for (int it = 0; it < 4; ++it) {  // A: 128 x 64
      int id = it * 256 + tid;
      int rd = id >> 3, cc = (id & 7) * 8;
      *(uint4*)(&ldsA[rd * 72 + cc]) =
          *(const uint4*)(base + rd * D_ + ec + cc);
    }
#pragma unroll
    for (int it = 0; it < 8; ++it) {  // B: 256 x 64
      int id = it * 256 + tid;
      int rd = id >> 3, cc = (id & 7) * 8;
      *(uint4*)(&ldsB[rd * 72 + cc]) =
          *(const uint4*)(WvT + rd * D_ + ec + cc);
    }
    __syncthreads();
#pragma unroll
    for (int kc = 0; kc < 64; kc += 32) {
      int ko = kc + quad * 8;
      short8 a[2][4], b[4];
#pragma unroll
      for (int m = 0; m < 2; ++m)
#pragma unroll
        for (int i = 0; i < 4; ++i)
          a[m][i] =
              *(const short8*)(&ldsA[(m * 64 + i * 16 + lane16) * 72 + ko]);
#pragma unroll
      for (int j = 0; j < 4; ++j)
        b[j] = *(const short8*)(&ldsB[(w * 64 + j * 16 + lane16) * 72 + ko]);
#pragma unroll
      for (int m = 0; m < 2; ++m)
#pragma unroll
        for (int i = 0; i < 4; ++i)
#pragma unroll
          for (int j = 0; j < 4; ++j)
            acc[m][i][j] = __builtin_amdgcn_mfma_f32_16x16x32_bf16(
                a[m][i], b[j], acc[m][i][j], 0, 0, 0);
    }
  }
  // epilogue: overwrite own region as [c][d_local], d_local 4-contiguous.
  // All global reads of this region finished (last staging + barrier above).
#pragma unroll
  for (int m = 0; m < 2; ++m) {
#pragma unroll
    for (int i = 0; i < 4; ++i) {
#pragma unroll
      for (int j = 0; j < 4; ++j) {
        int c = w * 64 + j * 16 + lane16;
        int d0 = m * 64 + i * 16 + quad * 4;
        float bvc = bv[c];
        ushort4 p;
        p.x = f2bf(acc[m][i][j][0] + bvc);
        p.y = f2bf(acc[m][i][j][1] + bvc);
        p.z = f2bf(acc[m][i][j][2] + bvc);
        p.w = f2bf(acc[m][i][j][3] + bvc);
        *(ushort4*)(base + c * 128 + d0) = p;
      }
    }
  }
}

// ---------------------------------------------------------------------------
// Kernel 6: out[bz][s][c] = sum_d qb[n][s][d] * kvWT'[bz](c,d)   (fp32 out)
// kvWT' lives in the kv0 buffer, half-major: element (c,d) at
//   bz*65536 + (d>>7)*32768 + c*128 + (d&127).
// C[m=s][n=c]: A = qb rows s, B = kvWT' rows c, both bf16, k=d.
// Bias already folded. Tile 128x128, grid (s-tile 4, c-tile 2, bz).
// ---------------------------------------------------------------------------
__global__ __launch_bounds__(256) void k_out(
    const ushort* __restrict__ qb, const ushort* __restrict__ kvw,
    float* __restrict__ out) {
  const int bx = blockIdx.x;  // s-tile (0..3)
  const int by = blockIdx.y;  // c-tile (0..1)
  const int bz = blockIdx.z;  // b*N+n
  const int n = bz % N_;
  const int tid = threadIdx.x;
  const int l = tid & 63, w = tid >> 6;
  const int wm = w & 1, wn = w >> 1;
  const int lane16 = l & 15, quad = l >> 4;

  __shared__ ushort ldsA[128 * 72];  // qb tile    [s_local][d_local]
  __shared__ ushort ldsB[128 * 72];  // kvWT' tile [c_local][d_local]

  float4v acc[4][4];
#pragma unroll
  for (int i = 0; i < 4; ++i)
#pragma unroll
    for (int j = 0; j < 4; ++j) acc[i][j] = (float4v)0.0f;

  const ushort* abase = qb + (size_t)n * S_ * D_ + bx * 128 * D_;
  const ushort* bbase = kvw + (size_t)bz * D_ * D_;

  for (int dc = 0; dc < D_; dc += 64) {
    __syncthreads();
#pragma unroll
    for (int it = 0; it < 4; ++it) {
      int id = it * 256 + tid;
      int rd = id >> 3, cc = (id & 7) * 8;
      *(uint4*)(&ldsA[rd * 72 + cc]) =
          *(const uint4*)(abase + rd * D_ + dc + cc);
    }
#pragma unroll
    for (int it = 0; it < 4; ++it) {
      int id = it * 256 + tid;
      int rd = id >> 3, cc = (id & 7) * 8;  // rd = c_local
      *(uint4*)(&ldsB[rd * 72 + cc]) =
          *(const uint4*)(bbase + (dc >> 7) * 32768 + (by * 128 + rd) * 128 +
                          (dc & 127) + cc);
    }
    __syncthreads();
#pragma unroll
    for (int kc = 0; kc < 64; kc += 32) {
      int ko = kc + quad * 8;
      short8 a[4], b[4];
#pragma unroll
      for (int i = 0; i < 4; ++i)
        a[i] = *(const short8*)(&ldsA[(wm * 64 + i * 16 + lane16) * 72 + ko]);
#pragma unroll
      for (int j = 0; j < 4; ++j)
        b[j] = *(const short8*)(&ldsB[(wn * 64 + j * 16 + lane16) * 72 + ko]);
#pragma unroll
      for (int i = 0; i < 4; ++i)
#pragma unroll
        for (int j = 0; j < 4; ++j)
          acc[i][j] = __builtin_amdgcn_mfma_f32_16x16x32_bf16(a[i], b[j],
                                                              acc[i][j], 0, 0, 0);
    }
  }
  // epilogue: row s = bx*128+wm*64+i*16+quad*4+r, col c = by*128+wn*64+j*16+lane16
  float* obase = out + (size_t)bz * S_ * D_;
#pragma unroll
  for (int i = 0; i < 4; ++i) {
#pragma unroll
    for (int j = 0; j < 4; ++j) {
      int s0 = bx * 128 + wm * 64 + i * 16 + quad * 4;
      int c = by * 128 + wn * 64 + j * 16 + lane16;
#pragma unroll
      for (int r = 0; r < 4; ++r)
        obase[(s0 + r) * D_ + c] = acc[i][j][r];
    }
  }
}

// ---------------------------------------------------------------------------
extern "C" void kernel_launch(void* const* d_in, const int* in_sizes, int n_in,
                              void* d_out, int out_size, void* d_ws,
                              size_t ws_size, hipStream_t stream) {
  const float* value = (const float*)d_in[0];  // [B,N,S,D]
  const float* emb   = (const float*)d_in[1];  // [N,S,A]
  const float* Wqk   = (const float*)d_in[2];  // [A,D]
  const float* bqk   = (const float*)d_in[3];  // [D]
  const float* Wv    = (const float*)d_in[4];  // [D,D]
  const float* bv    = (const float*)d_in[5];  // [D]
  float* out = (float*)d_out;

  // ws layout (bytes) — total 63,045,632 B, identical to proven baseline:
  //   qk fp32   [0,         6291456)
  //   qb bf16   [6291456,   9437184)
  //   kTb bf16  [9437184,   12582912)
  //   kv0/kvWT  [12582912,  62914560)   k4 out [bz][d][e]; k5 rewrites in-place
  //   WvT bf16  [62914560,  63045632)
  char* ws = (char*)d_ws;
  float*  qk  = (float*)ws;
  ushort* qb  = (ushort*)(ws + 6291456);
  ushort* kTb = (ushort*)(ws + 9437184);
  ushort* kv0 = (ushort*)(ws + 12582912);
  ushort* WvT = (ushort*)(ws + 62914560);

  k_qk_softmax_q<<<dim3(N_ * S_), 256, 0, stream>>>(emb, Wqk, bqk, qk, qb);
  k_softmax_kT<<<dim3(D_, N_), 256, 0, stream>>>(qk, kTb);
  k_wvt<<<dim3(D_), 256, 0, stream>>>(Wv, WvT);
  k_kv0<<<dim3(4, B_ * N_), 256, 0, stream>>>(kTb, value, kv0);
  k_kvw_inplace<<<dim3(2, B_ * N_), 256, 0, stream>>>(kv0, WvT, bv);
  k_out<<<dim3(4, 2, B_ * N_), 256, 0, stream>>>(qb, kv0, out);
}

// Round 3
// 445.603 us; speedup vs baseline: 1.0865x; 1.0601x over previous
//
#include <hip/hip_runtime.h>
#include <hip/hip_bf16.h>

// Shapes (fixed by reference): B=32, N=12, S=512, D=256, A=96
#define B_ 32
#define N_ 12
#define S_ 512
#define D_ 256
#define A_ 96

typedef __attribute__((ext_vector_type(8))) short short8;   // 8 bf16 (4 VGPRs)
typedef __attribute__((ext_vector_type(4))) float float4v;  // MFMA acc

// fp32 -> bf16 round-to-nearest-even (data has no NaN/Inf)
static __device__ __forceinline__ ushort f2bf(float f) {
  union { float f; unsigned u; } a;
  a.f = f;
  return (ushort)((a.u + 0x7FFFu + ((a.u >> 16) & 1u)) >> 16);
}

// ---------------------------------------------------------------------------
// Kernel 1: qk = emb @ Wqk + bqk  [N,S,D] fp32 (for kernel 2), and
//           q = softmax(qk, d) written bf16 [n][s][d].
// 8 s-rows per block: Wqk loaded once per 8 rows (L2 traffic /8), emb rows
// staged transposed seT[a][r] so the k-loop uses 2 broadcast ds_read_b128.
// ---------------------------------------------------------------------------
__global__ __launch_bounds__(256) void k_qk_softmax_q(
    const float* __restrict__ emb, const float* __restrict__ Wqk,
    const float* __restrict__ bqk, float* __restrict__ qk,
    ushort* __restrict__ qb) {
  const int blk = blockIdx.x;  // 768 blocks, 8 rows each (rows never straddle n)
  const int tid = threadIdx.x;
  const int d = tid;
  const int wv = tid >> 6, lane = tid & 63;
  __shared__ float seT[A_][8];  // [a][r]
  __shared__ float redm[8][4], reds[8][4];
  const float* ebase = emb + (size_t)blk * 8 * A_;
  for (int k = tid; k < 8 * A_; k += 256) {
    int r = k / A_, a = k - r * A_;
    seT[a][r] = ebase[k];
  }
  __syncthreads();
  float bq = bqk[d];
  float acc[8];
#pragma unroll
  for (int r = 0; r < 8; ++r) acc[r] = bq;
#pragma unroll 8
  for (int a = 0; a < A_; ++a) {
    float w = Wqk[a * D_ + d];
    float4 lo = *(const float4*)(&seT[a][0]);
    float4 hi = *(const float4*)(&seT[a][4]);
    acc[0] = fmaf(lo.x, w, acc[0]);
    acc[1] = fmaf(lo.y, w, acc[1]);
    acc[2] = fmaf(lo.z, w, acc[2]);
    acc[3] = fmaf(lo.w, w, acc[3]);
    acc[4] = fmaf(hi.x, w, acc[4]);
    acc[5] = fmaf(hi.y, w, acc[5]);
    acc[6] = fmaf(hi.z, w, acc[6]);
    acc[7] = fmaf(hi.w, w, acc[7]);
  }
  const size_t obase = (size_t)blk * 8 * D_ + d;
#pragma unroll
  for (int r = 0; r < 8; ++r) qk[obase + r * D_] = acc[r];
  // per-row max over d (256 threads): wave shfl + LDS cross-wave
  float m[8];
#pragma unroll
  for (int r = 0; r < 8; ++r) {
    m[r] = acc[r];
    for (int off = 32; off; off >>= 1) m[r] = fmaxf(m[r], __shfl_xor(m[r], off));
  }
  if (lane == 0) {
#pragma unroll
    for (int r = 0; r < 8; ++r) redm[r][wv] = m[r];
  }
  __syncthreads();
  float e[8], s[8];
#pragma unroll
  for (int r = 0; r < 8; ++r) {
    float mm = fmaxf(fmaxf(redm[r][0], redm[r][1]),
                     fmaxf(redm[r][2], redm[r][3]));
    e[r] = __expf(acc[r] - mm);
    s[r] = e[r];
    for (int off = 32; off; off >>= 1) s[r] += __shfl_xor(s[r], off);
  }
  if (lane == 0) {
#pragma unroll
    for (int r = 0; r < 8; ++r) reds[r][wv] = s[r];
  }
  __syncthreads();
#pragma unroll
  for (int r = 0; r < 8; ++r) {
    float sum = reds[r][0] + reds[r][1] + reds[r][2] + reds[r][3];
    qb[obase + r * D_] = f2bf(e[r] / sum);
  }
}

// ---------------------------------------------------------------------------
// Kernel 2: kT[n][d][s] = softmax over s of qk[n][s][d], bf16 output.
// Coalesced rewrite: block = (16-d chunk, n); float4 loads -> LDS transpose
// t[d][s] (pad 514 -> 2-way on writes); thread (d,sg) owns s = sg+16k;
// 16-lane shfl reductions (threads of one d are 16 consecutive lanes).
// ---------------------------------------------------------------------------
__global__ __launch_bounds__(256) void k_softmax_kT(
    const float* __restrict__ qk, ushort* __restrict__ kTb) {
  const int dc = blockIdx.x * 16;  // d-chunk base (grid.x = 16)
  const int n = blockIdx.y;
  const int tid = threadIdx.x;
  __shared__ float t[16][514];
  const float* base = qk + (size_t)n * S_ * D_ + dc;
#pragma unroll
  for (int it = 0; it < 8; ++it) {  // 2048 float4s: 16 d x 512 s
    int id = it * 256 + tid;
    int d4 = id & 3, s = id >> 2;
    float4 v = *(const float4*)(base + (size_t)s * D_ + 4 * d4);
    t[4 * d4 + 0][s] = v.x;
    t[4 * d4 + 1][s] = v.y;
    t[4 * d4 + 2][s] = v.z;
    t[4 * d4 + 3][s] = v.w;
  }
  __syncthreads();
  const int d = tid >> 4, sg = tid & 15;
  float vv[32];
  float m = -1e30f;
#pragma unroll
  for (int k = 0; k < 32; ++k) {
    vv[k] = t[d][sg + 16 * k];
    m = fmaxf(m, vv[k]);
  }
  for (int off = 1; off < 16; off <<= 1) m = fmaxf(m, __shfl_xor(m, off));
  float sum = 0.0f;
#pragma unroll
  for (int k = 0; k < 32; ++k) {
    vv[k] = __expf(vv[k] - m);
    sum += vv[k];
  }
  for (int off = 1; off < 16; off <<= 1) sum += __shfl_xor(sum, off);
  float inv = 1.0f / sum;
  const size_t ob = ((size_t)n * D_ + dc + d) * S_;
#pragma unroll
  for (int k = 0; k < 32; ++k) kTb[ob + sg + 16 * k] = f2bf(vv[k] * inv);
}

// ---------------------------------------------------------------------------
// Kernel 3: WvT[c][e] = bf16(Wv[e][c])  (tiny: 256x256)
// ---------------------------------------------------------------------------
__global__ __launch_bounds__(256) void k_wvt(const float* __restrict__ Wv,
                                             ushort* __restrict__ WvT) {
  int c = blockIdx.x, e = threadIdx.x;
  WvT[c * D_ + e] = f2bf(Wv[e * D_ + c]);
}

// ---------------------------------------------------------------------------
// Kernel 4: kv0[bz][d][e] = sum_s kT[n][d][s] * value[bz][s][e]  (bf16 MFMA)
// C[m=e][n=d]: A = value^T rows e (transpose+cvt staging), B = kT rows d.
// Block: e-tile 64 (blockIdx.x 0..3) x FULL d=256 -> value read exactly ONCE.
// 4 waves split n=d (64 each); per-wave 64x64 = acc[4][4]; BK=64.
// V staging: 4 s-rows per thread -> 4x ushort4 (b64) LDS writes (was 8x b32
// at the same 8-way row-bank conflict -> conflicted-issue cost halved).
// ---------------------------------------------------------------------------
__global__ __launch_bounds__(256) void k_kv0(
    const ushort* __restrict__ kTb, const float* __restrict__ value,
    ushort* __restrict__ kv0) {
  const int eb = blockIdx.x * 64;  // e-tile base (0..3)
  const int bz = blockIdx.y;       // b*N+n
  const int n = bz % N_;
  const int tid = threadIdx.x;
  const int l = tid & 63, w = tid >> 6;
  const int lane16 = l & 15, quad = l >> 4;

  __shared__ ushort ldsV[64 * 72];   // valueT tile [e_local][s_local]
  __shared__ ushort ldsK[256 * 72];  // kT tile     [d][s_local]

  float4v acc[4][4];
#pragma unroll
  for (int i = 0; i < 4; ++i)
#pragma unroll
    for (int j = 0; j < 4; ++j) acc[i][j] = (float4v)0.0f;

  const ushort* kTbase = kTb + (size_t)n * D_ * S_;
  const float* vbase = value + (size_t)bz * S_ * D_ + eb;

  for (int sc = 0; sc < S_; sc += 64) {
    __syncthreads();
    // stage K: 256 rows x 64 cols bf16, natural copy, 16B chunks
#pragma unroll
    for (int it = 0; it < 8; ++it) {
      int id = it * 256 + tid;
      int rd = id >> 3, cc = (id & 7) * 8;
      *(uint4*)(&ldsK[rd * 72 + cc]) =
          *(const uint4*)(kTbase + rd * S_ + sc + cc);
    }
    // stage V transposed: 4 coalesced s-rows per thread, one ushort4 write
#pragma unroll
    for (int it = 0; it < 4; ++it) {
      int id = it * 256 + tid;
      int e = id & 63, sq = id >> 6;  // s-quad 0..15
      float f0 = vbase[(sc + 4 * sq + 0) * D_ + e];
      float f1 = vbase[(sc + 4 * sq + 1) * D_ + e];
      float f2 = vbase[(sc + 4 * sq + 2) * D_ + e];
      float f3 = vbase[(sc + 4 * sq + 3) * D_ + e];
      ushort4 p;
      p.x = f2bf(f0);
      p.y = f2bf(f1);
      p.z = f2bf(f2);
      p.w = f2bf(f3);
      *(ushort4*)(&ldsV[e * 72 + 4 * sq]) = p;
    }
    __syncthreads();
#pragma unroll
    for (int kc = 0; kc < 64; kc += 32) {
      int ko = kc + quad * 8;
      short8 a[4], b[4];
#pragma unroll
      for (int i = 0; i < 4; ++i)  // A rows m = e_local
        a[i] = *(const short8*)(&ldsV[(i * 16 + lane16) * 72 + ko]);
#pragma unroll
      for (int j = 0; j < 4; ++j)  // B rows n = d
        b[j] = *(const short8*)(&ldsK[(w * 64 + j * 16 + lane16) * 72 + ko]);
#pragma unroll
      for (int i = 0; i < 4; ++i)
#pragma unroll
        for (int j = 0; j < 4; ++j)
          acc[i][j] = __builtin_amdgcn_mfma_f32_16x16x32_bf16(a[i], b[j],
                                                              acc[i][j], 0, 0, 0);
    }
  }
  // epilogue: n = d = w*64+j*16+lane16; m = e = eb+i*16+quad*4+r -> kv0[d][e]
  ushort* obase = kv0 + (size_t)bz * D_ * D_;
#pragma unroll
  for (int i = 0; i < 4; ++i) {
#pragma unroll
    for (int j = 0; j < 4; ++j) {
      int d = w * 64 + j * 16 + lane16;
      int e0 = eb + i * 16 + quad * 4;
      ushort4 p;
      p.x = f2bf(acc[i][j][0]);
      p.y = f2bf(acc[i][j][1]);
      p.z = f2bf(acc[i][j][2]);
      p.w = f2bf(acc[i][j][3]);
      *(ushort4*)(obase + d * D_ + e0) = p;
    }
  }
}

// ---------------------------------------------------------------------------
// Kernel 5: IN-PLACE kvW transform, d-QUARTER granularity (63 MB ws kept).
//   Block (qd, bz) owns rows d in [64qd, 64qd+64) of kv0[bz] (16384 elems):
//   reads ONLY that region (+WvT), overwrites it as kvWT'[c][d_local] with
//   kvW = kv0 @ Wv + bv (bias folds exactly: softmax rows of q sum to 1).
// Race-free: row d of kv0@Wv depends only on row d of kv0; single owner per
// region; staging reads complete before epilogue (barrier); k4->k5->k6
// stream-ordered.  46 KB LDS -> 3 blocks/CU; grid (4,384) = 2 clean rounds.
// C[m=d_local][n=c]: A = kv0 rows d (natural), B = WvT rows c (natural).
// 4 waves along c (64 each); acc[4][4]; BK=64.
// ---------------------------------------------------------------------------
__global__ __launch_bounds__(256) void k_kvw_inplace(
    ushort* kv0, const ushort* __restrict__ WvT,
    const float* __restrict__ bv) {
  const int qd = blockIdx.x;  // d-quarter (0..3)
  const int bz = blockIdx.y;  // b*N+n
  const int tid = threadIdx.x;
  const int l = tid & 63, w = tid >> 6;
  const int lane16 = l & 15, quad = l >> 4;

  __shared__ ushort ldsA[64 * 72];   // kv0 rows d_local x e-chunk
  __shared__ ushort ldsB[256 * 72];  // WvT rows c x e-chunk

  float4v acc[4][4];
#pragma unroll
  for (int i = 0; i < 4; ++i)
#pragma unroll
    for (int j = 0; j < 4; ++j) acc[i][j] = (float4v)0.0f;

  ushort* base = kv0 + (size_t)bz * (D_ * D_) + qd * (64 * D_);

  for (int ec = 0; ec < D_; ec += 64) {
    __syncthreads();
#pragma unroll
    for (int it = 0; it < 2; ++it) {  // A: 64 x 64
      int id = it * 256 + tid;
      int rd = id >> 3, cc = (id & 7) * 8;
      *(uint4*)(&ldsA[rd * 72 + cc]) =
          *(const uint4*)(base + rd * D_ + ec + cc);
    }
#pragma unroll
    for (int it = 0; it < 8; ++it) {  // B: 256 x 64
      int id = it * 256 + tid;
      int rd = id >> 3, cc = (id & 7) * 8;
      *(uint4*)(&ldsB[rd * 72 + cc]) =
          *(const uint4*)(WvT + rd * D_ + ec + cc);
    }
    __syncthreads();
#pragma unroll
    for (int kc = 0; kc < 64; kc += 32) {
      int ko = kc + quad * 8;
      short8 a[4], b[4];
#pragma unroll
      for (int i = 0; i < 4; ++i)
        a[i] = *(const short8*)(&ldsA[(i * 16 + lane16) * 72 + ko]);
#pragma unroll
      for (int j = 0; j < 4; ++j)
        b[j] = *(const short8*)(&ldsB[(w * 64 + j * 16 + lane16) * 72 + ko]);
#pragma unroll
      for (int i = 0; i < 4; ++i)
#pragma unroll
        for (int j = 0; j < 4; ++j)
          acc[i][j] = __builtin_amdgcn_mfma_f32_16x16x32_bf16(a[i], b[j],
                                                              acc[i][j], 0, 0, 0);
    }
  }
  // epilogue: overwrite own 16384-elem region as [c][d_local] (64-wide rows),
  // d_local 4-contiguous.  All global reads of the region completed above.
#pragma unroll
  for (int i = 0; i < 4; ++i) {
#pragma unroll
    for (int j = 0; j < 4; ++j) {
      int c = w * 64 + j * 16 + lane16;
      int d0 = i * 16 + quad * 4;
      float bvc = bv[c];
      ushort4 p;
      p.x = f2bf(acc[i][j][0] + bvc);
      p.y = f2bf(acc[i][j][1] + bvc);
      p.z = f2bf(acc[i][j][2] + bvc);
      p.w = f2bf(acc[i][j][3] + bvc);
      *(ushort4*)(base + c * 64 + d0) = p;
    }
  }
}

// ---------------------------------------------------------------------------
// Kernel 6: out[bz][s][c] = sum_d qb[n][s][d] * kvWT'[bz](c,d)   (fp32 out)
// kvWT' lives in the kv0 buffer, quarter-major: element (c,d) at
//   bz*65536 + (d>>6)*16384 + c*64 + (d&63).
// C[m=s][n=c]: A = qb rows s, B = kvWT' rows c, both bf16, k=d.
// Bias already folded. Tile 128x128, grid (s-tile 4, c-tile 2, bz).
// ---------------------------------------------------------------------------
__global__ __launch_bounds__(256) void k_out(
    const ushort* __restrict__ qb, const ushort* __restrict__ kvw,
    float* __restrict__ out) {
  const int bx = blockIdx.x;  // s-tile (0..3)
  const int by = blockIdx.y;  // c-tile (0..1)
  const int bz = blockIdx.z;  // b*N+n
  const int n = bz % N_;
  const int tid = threadIdx.x;
  const int l = tid & 63, w = tid >> 6;
  const int wm = w & 1, wn = w >> 1;
  const int lane16 = l & 15, quad = l >> 4;

  __shared__ ushort ldsA[128 * 72];  // qb tile    [s_local][d_local]
  __shared__ ushort ldsB[128 * 72];  // kvWT' tile [c_local][d_local]

  float4v acc[4][4];
#pragma unroll
  for (int i = 0; i < 4; ++i)
#pragma unroll
    for (int j = 0; j < 4; ++j) acc[i][j] = (float4v)0.0f;

  const ushort* abase = qb + (size_t)n * S_ * D_ + bx * 128 * D_;
  const ushort* bbase = kvw + (size_t)bz * D_ * D_;

  for (int dc = 0; dc < D_; dc += 64) {
    __syncthreads();
#pragma unroll
    for (int it = 0; it < 4; ++it) {
      int id = it * 256 + tid;
      int rd = id >> 3, cc = (id & 7) * 8;
      *(uint4*)(&ldsA[rd * 72 + cc]) =
          *(const uint4*)(abase + rd * D_ + dc + cc);
    }
#pragma unroll
    for (int it = 0; it < 4; ++it) {
      int id = it * 256 + tid;
      int rd = id >> 3, cc = (id & 7) * 8;  // rd = c_local; dc&63 == 0
      *(uint4*)(&ldsB[rd * 72 + cc]) =
          *(const uint4*)(bbase + (dc >> 6) * 16384 + (by * 128 + rd) * 64 +
                          cc);
    }
    __syncthreads();
#pragma unroll
    for (int kc = 0; kc < 64; kc += 32) {
      int ko = kc + quad * 8;
      short8 a[4], b[4];
#pragma unroll
      for (int i = 0; i < 4; ++i)
        a[i] = *(const short8*)(&ldsA[(wm * 64 + i * 16 + lane16) * 72 + ko]);
#pragma unroll
      for (int j = 0; j < 4; ++j)
        b[j] = *(const short8*)(&ldsB[(wn * 64 + j * 16 + lane16) * 72 + ko]);
#pragma unroll
      for (int i = 0; i < 4; ++i)
#pragma unroll
        for (int j = 0; j < 4; ++j)
          acc[i][j] = __builtin_amdgcn_mfma_f32_16x16x32_bf16(a[i], b[j],
                                                              acc[i][j], 0, 0, 0);
    }
  }
  // epilogue: row s = bx*128+wm*64+i*16+quad*4+r, col c = by*128+wn*64+j*16+lane16
  float* obase = out + (size_t)bz * S_ * D_;
#pragma unroll
  for (int i = 0; i < 4; ++i) {
#pragma unroll
    for (int j = 0; j < 4; ++j) {
      int s0 = bx * 128 + wm * 64 + i * 16 + quad * 4;
      int c = by * 128 + wn * 64 + j * 16 + lane16;
#pragma unroll
      for (int r = 0; r < 4; ++r)
        obase[(s0 + r) * D_ + c] = acc[i][j][r];
    }
  }
}

// ---------------------------------------------------------------------------
extern "C" void kernel_launch(void* const* d_in, const int* in_sizes, int n_in,
                              void* d_out, int out_size, void* d_ws,
                              size_t ws_size, hipStream_t stream) {
  const float* value = (const float*)d_in[0];  // [B,N,S,D]
  const float* emb   = (const float*)d_in[1];  // [N,S,A]
  const float* Wqk   = (const float*)d_in[2];  // [A,D]
  const float* bqk   = (const float*)d_in[3];  // [D]
  const float* Wv    = (const float*)d_in[4];  // [D,D]
  const float* bv    = (const float*)d_in[5];  // [D]
  float* out = (float*)d_out;

  // ws layout (bytes) — total 63,045,632 B (proven size):
  //   qk fp32   [0,         6291456)
  //   qb bf16   [6291456,   9437184)
  //   kTb bf16  [9437184,   12582912)
  //   kv0/kvWT  [12582912,  62914560)   k4 out [bz][d][e]; k5 rewrites in-place
  //   WvT bf16  [62914560,  63045632)
  char* ws = (char*)d_ws;
  float*  qk  = (float*)ws;
  ushort* qb  = (ushort*)(ws + 6291456);
  ushort* kTb = (ushort*)(ws + 9437184);
  ushort* kv0 = (ushort*)(ws + 12582912);
  ushort* WvT = (ushort*)(ws + 62914560);

  k_qk_softmax_q<<<dim3(N_ * S_ / 8), 256, 0, stream>>>(emb, Wqk, bqk, qk, qb);
  k_softmax_kT<<<dim3(16, N_), 256, 0, stream>>>(qk, kTb);
  k_wvt<<<dim3(D_), 256, 0, stream>>>(Wv, WvT);
  k_kv0<<<dim3(4, B_ * N_), 256, 0, stream>>>(kTb, value, kv0);
  k_kvw_inplace<<<dim3(4, B_ * N_), 256, 0, stream>>>(kv0, WvT, bv);
  k_out<<<dim3(4, 2, B_ * N_), 256, 0, stream>>>(qb, kv0, out);
}

// Round 4
// 439.828 us; speedup vs baseline: 1.1007x; 1.0131x over previous
//
#include <hip/hip_runtime.h>
#include <hip/hip_bf16.h>

// Shapes (fixed by reference): B=32, N=12, S=512, D=256, A=96
#define B_ 32
#define N_ 12
#define S_ 512
#define D_ 256
#define A_ 96

typedef __attribute__((ext_vector_type(8))) short short8;   // 8 bf16 (4 VGPRs)
typedef __attribute__((ext_vector_type(4))) float float4v;  // MFMA acc

// fp32 -> bf16 round-to-nearest-even (data has no NaN/Inf)
static __device__ __forceinline__ ushort f2bf(float f) {
  union { float f; unsigned u; } a;
  a.f = f;
  return (ushort)((a.u + 0x7FFFu + ((a.u >> 16) & 1u)) >> 16);
}

// ---------------------------------------------------------------------------
// Kernel 1: qk = emb @ Wqk + bqk  [N,S,D] fp32 (for kernel 2), and
//           q = softmax(qk, d) written bf16 [n][s][d].
// 8 s-rows per block: Wqk loaded once per 8 rows, emb staged transposed.
// ---------------------------------------------------------------------------
__global__ __launch_bounds__(256) void k_qk_softmax_q(
    const float* __restrict__ emb, const float* __restrict__ Wqk,
    const float* __restrict__ bqk, float* __restrict__ qk,
    ushort* __restrict__ qb) {
  const int blk = blockIdx.x;  // 768 blocks, 8 rows each (rows never straddle n)
  const int tid = threadIdx.x;
  const int d = tid;
  const int wv = tid >> 6, lane = tid & 63;
  __shared__ float seT[A_][8];  // [a][r]
  __shared__ float redm[8][4], reds[8][4];
  const float* ebase = emb + (size_t)blk * 8 * A_;
  for (int k = tid; k < 8 * A_; k += 256) {
    int r = k / A_, a = k - r * A_;
    seT[a][r] = ebase[k];
  }
  __syncthreads();
  float bq = bqk[d];
  float acc[8];
#pragma unroll
  for (int r = 0; r < 8; ++r) acc[r] = bq;
#pragma unroll 8
  for (int a = 0; a < A_; ++a) {
    float w = Wqk[a * D_ + d];
    float4 lo = *(const float4*)(&seT[a][0]);
    float4 hi = *(const float4*)(&seT[a][4]);
    acc[0] = fmaf(lo.x, w, acc[0]);
    acc[1] = fmaf(lo.y, w, acc[1]);
    acc[2] = fmaf(lo.z, w, acc[2]);
    acc[3] = fmaf(lo.w, w, acc[3]);
    acc[4] = fmaf(hi.x, w, acc[4]);
    acc[5] = fmaf(hi.y, w, acc[5]);
    acc[6] = fmaf(hi.z, w, acc[6]);
    acc[7] = fmaf(hi.w, w, acc[7]);
  }
  const size_t obase = (size_t)blk * 8 * D_ + d;
#pragma unroll
  for (int r = 0; r < 8; ++r) qk[obase + r * D_] = acc[r];
  float m[8];
#pragma unroll
  for (int r = 0; r < 8; ++r) {
    m[r] = acc[r];
    for (int off = 32; off; off >>= 1) m[r] = fmaxf(m[r], __shfl_xor(m[r], off));
  }
  if (lane == 0) {
#pragma unroll
    for (int r = 0; r < 8; ++r) redm[r][wv] = m[r];
  }
  __syncthreads();
  float e[8], s[8];
#pragma unroll
  for (int r = 0; r < 8; ++r) {
    float mm = fmaxf(fmaxf(redm[r][0], redm[r][1]),
                     fmaxf(redm[r][2], redm[r][3]));
    e[r] = __expf(acc[r] - mm);
    s[r] = e[r];
    for (int off = 32; off; off >>= 1) s[r] += __shfl_xor(s[r], off);
  }
  if (lane == 0) {
#pragma unroll
    for (int r = 0; r < 8; ++r) reds[r][wv] = s[r];
  }
  __syncthreads();
#pragma unroll
  for (int r = 0; r < 8; ++r) {
    float sum = reds[r][0] + reds[r][1] + reds[r][2] + reds[r][3];
    qb[obase + r * D_] = f2bf(e[r] / sum);
  }
}

// ---------------------------------------------------------------------------
// Kernel 2: kT[n][d][s] = softmax over s of qk[n][s][d], bf16 output.
// Coalesced: block = (16-d chunk, n); float4 loads -> LDS transpose.
// ---------------------------------------------------------------------------
__global__ __launch_bounds__(256) void k_softmax_kT(
    const float* __restrict__ qk, ushort* __restrict__ kTb) {
  const int dc = blockIdx.x * 16;  // d-chunk base (grid.x = 16)
  const int n = blockIdx.y;
  const int tid = threadIdx.x;
  __shared__ float t[16][514];
  const float* base = qk + (size_t)n * S_ * D_ + dc;
#pragma unroll
  for (int it = 0; it < 8; ++it) {  // 2048 float4s: 16 d x 512 s
    int id = it * 256 + tid;
    int d4 = id & 3, s = id >> 2;
    float4 v = *(const float4*)(base + (size_t)s * D_ + 4 * d4);
    t[4 * d4 + 0][s] = v.x;
    t[4 * d4 + 1][s] = v.y;
    t[4 * d4 + 2][s] = v.z;
    t[4 * d4 + 3][s] = v.w;
  }
  __syncthreads();
  const int d = tid >> 4, sg = tid & 15;
  float vv[32];
  float m = -1e30f;
#pragma unroll
  for (int k = 0; k < 32; ++k) {
    vv[k] = t[d][sg + 16 * k];
    m = fmaxf(m, vv[k]);
  }
  for (int off = 1; off < 16; off <<= 1) m = fmaxf(m, __shfl_xor(m, off));
  float sum = 0.0f;
#pragma unroll
  for (int k = 0; k < 32; ++k) {
    vv[k] = __expf(vv[k] - m);
    sum += vv[k];
  }
  for (int off = 1; off < 16; off <<= 1) sum += __shfl_xor(sum, off);
  float inv = 1.0f / sum;
  const size_t ob = ((size_t)n * D_ + dc + d) * S_;
#pragma unroll
  for (int k = 0; k < 32; ++k) kTb[ob + sg + 16 * k] = f2bf(vv[k] * inv);
}

// ---------------------------------------------------------------------------
// Kernel 3: WvT[c][e] = bf16(Wv[e][c])  (tiny: 256x256)
// ---------------------------------------------------------------------------
__global__ __launch_bounds__(256) void k_wvt(const float* __restrict__ Wv,
                                             ushort* __restrict__ WvT) {
  int c = blockIdx.x, e = threadIdx.x;
  WvT[c * D_ + e] = f2bf(Wv[e * D_ + c]);
}

// ---------------------------------------------------------------------------
// Kernel 4 (FUSED kv + kvW): one block per (d-half h, bz), 512 threads/8 waves.
// Stage 1: kv0_half[d_local 128][e 256] = kT[h*128+d][s] * value[bz][s][e],
//          accumulated over s in 8 steps of 64; kv0_half parked in LDS
//          (stride 280, never hits HBM).
// Stage 2: kvW_half[d][c] = sum_e kv0_half[d][e]*Wv[e][c] + bv[c]
//          (bias folds exactly: softmax rows of q sum to 1); written to the
//          kvw buffer in quarter-major layout for k_out:
//          (c,d) at bz*65536 + (d>>6)*16384 + c*64 + (d&63).
// Wave grid both stages: wd = w&1 (d 64-range), we = w>>1 (e/c 64-range).
// XCD swizzle: 768 blocks, the 2 d-half blocks of one bz share value[bz]
// (512 KB < 4 MB L2) -> map them to the same XCD, temporally adjacent.
// LDS: stage1 ldsK[128][72] @0 + ldsV[256][72] @18432B; stage2
// ldsKV[128][280] @0 (over stage1, after barrier) + ldsW[256][72] @71680B.
// Total 108,544 B -> 1 block/CU; grid 768 = 3 clean rounds.
// ---------------------------------------------------------------------------
__global__ __launch_bounds__(512) void k_kv_fused(
    const ushort* __restrict__ kTb, const float* __restrict__ value,
    const ushort* __restrict__ WvT, const float* __restrict__ bv,
    ushort* __restrict__ kvw) {
  // bijective XCD swizzle (768 % 8 == 0): same-bz pair lands on one XCD
  const int f = blockIdx.x;
  const int wk = (f & 7) * 96 + (f >> 3);
  const int h = wk & 1;         // d-half (0..1)
  const int bz = wk >> 1;       // b*N+n
  const int n = bz % N_;
  const int tid = threadIdx.x;
  const int l = tid & 63, w = tid >> 6;
  const int wd = w & 1, we = w >> 1;  // wave grid 2x4
  const int lane16 = l & 15, quad = l >> 4;

  __shared__ ushort smem[54272];      // 108,544 B
  ushort* ldsK = smem;                // [128][72] stage1 kT
  ushort* ldsV = smem + 9216;         // [256][72] stage1 value^T
  ushort* ldsKV = smem;               // [128][280] stage2 A (after barrier)
  ushort* ldsW = smem + 35840;        // [256][72] stage2 WvT chunk

  float4v acc[4][4];
#pragma unroll
  for (int i = 0; i < 4; ++i)
#pragma unroll
    for (int j = 0; j < 4; ++j) acc[i][j] = (float4v)0.0f;

  const ushort* kTbase = kTb + ((size_t)(n * D_ + h * 128)) * S_;
  const float* vbase = value + (size_t)bz * S_ * D_;

  // ---- stage 1: kv0_half over s ----
  for (int sc = 0; sc < S_; sc += 64) {
    __syncthreads();
    // stage kT half: 128 rows x 64 cols bf16 (1024 uint4 / 512 thr)
#pragma unroll
    for (int it = 0; it < 2; ++it) {
      int id = it * 512 + tid;
      int rd = id >> 3, cc = (id & 7) * 8;
      *(uint4*)(&ldsK[rd * 72 + cc]) =
          *(const uint4*)(kTbase + rd * S_ + sc + cc);
    }
    // stage V transposed: e rows 0..255, 4 coalesced s-rows per thread-id
#pragma unroll
    for (int it = 0; it < 8; ++it) {
      int id = it * 512 + tid;
      int e = id & 255, sq = id >> 8;  // sq 0..15
      float f0 = vbase[(sc + 4 * sq + 0) * D_ + e];
      float f1 = vbase[(sc + 4 * sq + 1) * D_ + e];
      float f2 = vbase[(sc + 4 * sq + 2) * D_ + e];
      float f3 = vbase[(sc + 4 * sq + 3) * D_ + e];
      ushort4 p;
      p.x = f2bf(f0);
      p.y = f2bf(f1);
      p.z = f2bf(f2);
      p.w = f2bf(f3);
      *(ushort4*)(&ldsV[e * 72 + 4 * sq]) = p;
    }
    __syncthreads();
#pragma unroll
    for (int kc = 0; kc < 64; kc += 32) {
      int ko = kc + quad * 8;
      short8 a[4], b[4];
#pragma unroll
      for (int i = 0; i < 4; ++i)  // A rows m = e
        a[i] = *(const short8*)(&ldsV[(we * 64 + i * 16 + lane16) * 72 + ko]);
#pragma unroll
      for (int j = 0; j < 4; ++j)  // B rows n = d_local
        b[j] = *(const short8*)(&ldsK[(wd * 64 + j * 16 + lane16) * 72 + ko]);
#pragma unroll
      for (int i = 0; i < 4; ++i)
#pragma unroll
        for (int j = 0; j < 4; ++j)
          acc[i][j] = __builtin_amdgcn_mfma_f32_16x16x32_bf16(a[i], b[j],
                                                              acc[i][j], 0, 0, 0);
    }
  }
  __syncthreads();  // all stage-1 LDS reads done before ldsKV overwrite
  // park kv0_half in LDS: d_local = wd*64+j*16+lane16, e0 = we*64+i*16+quad*4
#pragma unroll
  for (int i = 0; i < 4; ++i) {
#pragma unroll
    for (int j = 0; j < 4; ++j) {
      int dl = wd * 64 + j * 16 + lane16;
      int e0 = we * 64 + i * 16 + quad * 4;
      ushort4 p;
      p.x = f2bf(acc[i][j][0]);
      p.y = f2bf(acc[i][j][1]);
      p.z = f2bf(acc[i][j][2]);
      p.w = f2bf(acc[i][j][3]);
      *(ushort4*)(&ldsKV[dl * 280 + e0]) = p;
    }
  }

  // ---- stage 2: kvW_half = kv0_half @ Wv (+bv) ----
  float4v acc2[4][4];
#pragma unroll
  for (int i = 0; i < 4; ++i)
#pragma unroll
    for (int j = 0; j < 4; ++j) acc2[i][j] = (float4v)0.0f;

  for (int ec = 0; ec < D_; ec += 64) {
    __syncthreads();  // iter0: ldsKV writes visible; else: prev ldsW reads done
#pragma unroll
    for (int it = 0; it < 4; ++it) {  // WvT chunk 256 x 64 (2048 uint4)
      int id = it * 512 + tid;
      int rd = id >> 3, cc = (id & 7) * 8;
      *(uint4*)(&ldsW[rd * 72 + cc]) = *(const uint4*)(WvT + rd * D_ + ec + cc);
    }
    __syncthreads();
#pragma unroll
    for (int kc = 0; kc < 64; kc += 32) {
      int ko = kc + quad * 8;
      short8 a[4], b[4];
#pragma unroll
      for (int i = 0; i < 4; ++i)  // A rows m = d_local (stride 280)
        a[i] = *(const short8*)(&ldsKV[(wd * 64 + i * 16 + lane16) * 280 + ec +
                                       ko]);
#pragma unroll
      for (int j = 0; j < 4; ++j)  // B rows n = c
        b[j] = *(const short8*)(&ldsW[(we * 64 + j * 16 + lane16) * 72 + ko]);
#pragma unroll
      for (int i = 0; i < 4; ++i)
#pragma unroll
        for (int j = 0; j < 4; ++j)
          acc2[i][j] = __builtin_amdgcn_mfma_f32_16x16x32_bf16(a[i], b[j],
                                                               acc2[i][j], 0, 0, 0);
    }
  }
  // epilogue: quarter q = h*2+wd; c = we*64+j*16+lane16; d6 = i*16+quad*4
  ushort* obase = kvw + (size_t)bz * (D_ * D_) + (h * 2 + wd) * 16384;
#pragma unroll
  for (int i = 0; i < 4; ++i) {
#pragma unroll
    for (int j = 0; j < 4; ++j) {
      int c = we * 64 + j * 16 + lane16;
      int d6 = i * 16 + quad * 4;
      float bvc = bv[c];
      ushort4 p;
      p.x = f2bf(acc2[i][j][0] + bvc);
      p.y = f2bf(acc2[i][j][1] + bvc);
      p.z = f2bf(acc2[i][j][2] + bvc);
      p.w = f2bf(acc2[i][j][3] + bvc);
      *(ushort4*)(obase + c * 64 + d6) = p;
    }
  }
}

// ---------------------------------------------------------------------------
// Kernel 5: out[bz][s][c] = sum_d qb[n][s][d] * kvW'[bz](c,d)   (fp32 out)
// kvW' quarter-major: (c,d) at bz*65536 + (d>>6)*16384 + c*64 + (d&63).
// C[m=s][n=c]: A = qb rows s, B = kvW' rows c, both bf16, k=d.
// Tile 128x128; 1D grid 3072 with XCD swizzle so the 4 s-tile blocks of one
// (by,bz) — which share the same 64 KB kvw half — land on one XCD (L2 hits).
// ---------------------------------------------------------------------------
__global__ __launch_bounds__(256) void k_out(
    const ushort* __restrict__ qb, const ushort* __restrict__ kvw,
    float* __restrict__ out) {
  const int f = blockIdx.x;                 // 0..3071 (3072 % 8 == 0)
  const int wk = (f & 7) * 384 + (f >> 3);  // bijective XCD swizzle
  const int bx = wk & 3;         // s-tile (0..3)
  const int by = (wk >> 2) & 1;  // c-tile (0..1)
  const int bz = wk >> 3;        // b*N+n
  const int n = bz % N_;
  const int tid = threadIdx.x;
  const int l = tid & 63, w = tid >> 6;
  const int wm = w & 1, wn = w >> 1;
  const int lane16 = l & 15, quad = l >> 4;

  __shared__ ushort ldsA[128 * 72];  // qb tile   [s_local][d_local]
  __shared__ ushort ldsB[128 * 72];  // kvW' tile [c_local][d_local]

  float4v acc[4][4];
#pragma unroll
  for (int i = 0; i < 4; ++i)
#pragma unroll
    for (int j = 0; j < 4; ++j) acc[i][j] = (float4v)0.0f;

  const ushort* abase = qb + (size_t)n * S_ * D_ + bx * 128 * D_;
  const ushort* bbase = kvw + (size_t)bz * D_ * D_;

  for (int dc = 0; dc < D_; dc += 64) {
    __syncthreads();
#pragma unroll
    for (int it = 0; it < 4; ++it) {
      int id = it * 256 + tid;
      int rd = id >> 3, cc = (id & 7) * 8;
      *(uint4*)(&ldsA[rd * 72 + cc]) =
          *(const uint4*)(abase + rd * D_ + dc + cc);
    }
#pragma unroll
    for (int it = 0; it < 4; ++it) {
      int id = it * 256 + tid;
      int rd = id >> 3, cc = (id & 7) * 8;  // rd = c_local; dc&63 == 0
      *(uint4*)(&ldsB[rd * 72 + cc]) =
          *(const uint4*)(bbase + (dc >> 6) * 16384 + (by * 128 + rd) * 64 +
                          cc);
    }
    __syncthreads();
#pragma unroll
    for (int kc = 0; kc < 64; kc += 32) {
      int ko = kc + quad * 8;
      short8 a[4], b[4];
#pragma unroll
      for (int i = 0; i < 4; ++i)
        a[i] = *(const short8*)(&ldsA[(wm * 64 + i * 16 + lane16) * 72 + ko]);
#pragma unroll
      for (int j = 0; j < 4; ++j)
        b[j] = *(const short8*)(&ldsB[(wn * 64 + j * 16 + lane16) * 72 + ko]);
#pragma unroll
      for (int i = 0; i < 4; ++i)
#pragma unroll
        for (int j = 0; j < 4; ++j)
          acc[i][j] = __builtin_amdgcn_mfma_f32_16x16x32_bf16(a[i], b[j],
                                                              acc[i][j], 0, 0, 0);
    }
  }
  float* obase = out + (size_t)bz * S_ * D_;
#pragma unroll
  for (int i = 0; i < 4; ++i) {
#pragma unroll
    for (int j = 0; j < 4; ++j) {
      int s0 = bx * 128 + wm * 64 + i * 16 + quad * 4;
      int c = by * 128 + wn * 64 + j * 16 + lane16;
#pragma unroll
      for (int r = 0; r < 4; ++r)
        obase[(s0 + r) * D_ + c] = acc[i][j][r];
    }
  }
}

// ---------------------------------------------------------------------------
extern "C" void kernel_launch(void* const* d_in, const int* in_sizes, int n_in,
                              void* d_out, int out_size, void* d_ws,
                              size_t ws_size, hipStream_t stream) {
  const float* value = (const float*)d_in[0];  // [B,N,S,D]
  const float* emb   = (const float*)d_in[1];  // [N,S,A]
  const float* Wqk   = (const float*)d_in[2];  // [A,D]
  const float* bqk   = (const float*)d_in[3];  // [D]
  const float* Wv    = (const float*)d_in[4];  // [D,D]
  const float* bv    = (const float*)d_in[5];  // [D]
  float* out = (float*)d_out;

  // ws layout (bytes) — total 63,045,632 B (proven size):
  //   qk fp32   [0,         6291456)
  //   qb bf16   [6291456,   9437184)
  //   kTb bf16  [9437184,   12582912)
  //   kvw bf16  [12582912,  62914560)   (quarter-major, bias folded)
  //   WvT bf16  [62914560,  63045632)
  char* ws = (char*)d_ws;
  float*  qk  = (float*)ws;
  ushort* qb  = (ushort*)(ws + 6291456);
  ushort* kTb = (ushort*)(ws + 9437184);
  ushort* kvw = (ushort*)(ws + 12582912);
  ushort* WvT = (ushort*)(ws + 62914560);

  k_qk_softmax_q<<<dim3(N_ * S_ / 8), 256, 0, stream>>>(emb, Wqk, bqk, qk, qb);
  k_softmax_kT<<<dim3(16, N_), 256, 0, stream>>>(qk, kTb);
  k_wvt<<<dim3(D_), 256, 0, stream>>>(Wv, WvT);
  k_kv_fused<<<dim3(2 * B_ * N_), 512, 0, stream>>>(kTb, value, WvT, bv, kvw);
  k_out<<<dim3(4 * 2 * B_ * N_), 256, 0, stream>>>(qb, kvw, out);
}